// Round 1
// baseline (348.055 us; speedup 1.0000x reference)
//
#include <hip/hip_runtime.h>

// DACGLSTMExpert: 18432 independent CGLSTM sequences, T=120, H=32, DIN=1.
// Layout: 32 lanes per sequence (lane = hidden index), 2 sequences per wave64.
// Weights held in registers (o-gate is dead code in the reference and skipped).
// h broadcast across the 32-lane group via ds_swizzle (bit-mode broadcast).

constexpr int T = 120;
constexpr int H = 32;
constexpr int NSEQ = 2048 * 9;        // 18432
constexpr int SEQ_PER_BLOCK = 8;      // 256 threads / 32 lanes per seq
constexpr int BLOCK = 256;

#define LOG2E 1.4426950408889634f

__device__ __forceinline__ float fast_rcp(float x) {
    return __builtin_amdgcn_rcpf(x);
}
__device__ __forceinline__ float fast_exp2(float x) {
    return __builtin_amdgcn_exp2f(x);
}
// sigmoid(x) = 1 / (1 + 2^(-x*log2e))
__device__ __forceinline__ float sigmoid_f(float x) {
    return fast_rcp(1.0f + fast_exp2(-LOG2E * x));
}
// tanh(x) = 1 - 2/(2^(2x*log2e) + 1)   (saturates correctly at +/-inf)
__device__ __forceinline__ float tanh_f(float x) {
    return 1.0f - 2.0f * fast_rcp(1.0f + fast_exp2(2.0f * LOG2E * x));
}

__global__ __launch_bounds__(BLOCK) void cglstm_kernel(
    const float* __restrict__ x,      // [NSEQ, T]
    const float* __restrict__ W_ih,   // [4H, 1]
    const float* __restrict__ W_hh,   // [4H, H]
    const float* __restrict__ b_ih,   // [4H]
    const float* __restrict__ b_hh,   // [4H]
    const float* __restrict__ W_cg_x, // [H, 1]
    const float* __restrict__ W_cg_h, // [H, H]
    const float* __restrict__ b_cg,   // [H]
    float* __restrict__ out)          // [NSEQ, H]
{
    __shared__ float xs[SEQ_PER_BLOCK * T];   // 3840 B

    const int tid = threadIdx.x;
    const int l   = tid & 31;          // hidden index within sequence
    const int sib = tid >> 5;          // sequence-in-block 0..7
    const int seq = blockIdx.x * SEQ_PER_BLOCK + sib;

    // --- stage this block's x rows into LDS (fully coalesced) ---
    const float* xblk = x + (size_t)blockIdx.x * SEQ_PER_BLOCK * T;
    for (int i = tid; i < SEQ_PER_BLOCK * T; i += BLOCK)
        xs[i] = xblk[i];

    // --- per-lane weights in registers (float4 vector loads) ---
    float whh_i[H], whh_f[H], whh_g[H], wch[H];
    {
        const float4* ri = (const float4*)(W_hh + (size_t)(0 * H + l) * H);
        const float4* rf = (const float4*)(W_hh + (size_t)(1 * H + l) * H);
        const float4* rg = (const float4*)(W_hh + (size_t)(2 * H + l) * H);
        const float4* rc = (const float4*)(W_cg_h + (size_t)l * H);
        #pragma unroll
        for (int q = 0; q < H / 4; ++q) {
            float4 vi = ri[q], vf = rf[q], vg = rg[q], vc = rc[q];
            whh_i[4*q+0] = vi.x; whh_i[4*q+1] = vi.y; whh_i[4*q+2] = vi.z; whh_i[4*q+3] = vi.w;
            whh_f[4*q+0] = vf.x; whh_f[4*q+1] = vf.y; whh_f[4*q+2] = vf.z; whh_f[4*q+3] = vf.w;
            whh_g[4*q+0] = vg.x; whh_g[4*q+1] = vg.y; whh_g[4*q+2] = vg.z; whh_g[4*q+3] = vg.w;
            wch[4*q+0]   = vc.x; wch[4*q+1]   = vc.y; wch[4*q+2]   = vc.z; wch[4*q+3]   = vc.w;
        }
    }
    const float wi_i = W_ih[0 * H + l];
    const float wi_f = W_ih[1 * H + l];
    const float wi_g = W_ih[2 * H + l];
    const float wcx  = W_cg_x[l];
    const float bi   = b_ih[0 * H + l] + b_hh[0 * H + l];
    const float bf   = b_ih[1 * H + l] + b_hh[1 * H + l];
    const float bg   = b_ih[2 * H + l] + b_hh[2 * H + l];
    const float bc   = b_cg[l];

    __syncthreads();

    float h = 0.0f, c = 0.0f;
    const float* xrow = xs + sib * T;

    // Broadcast h from lane J of each 32-lane group: ds_swizzle bit-mode,
    // offset = (xor<<10)|(or<<5)|and with and=0, or=J, xor=0  ->  J<<5.
    #define STEP_J(J)                                                            \
    {                                                                            \
        float hj = __uint_as_float(                                              \
            (unsigned)__builtin_amdgcn_ds_swizzle(__float_as_uint(h), (J) << 5));\
        ai = fmaf(hj, whh_i[J], ai);                                             \
        af = fmaf(hj, whh_f[J], af);                                             \
        ag = fmaf(hj, whh_g[J], ag);                                             \
        ac = fmaf(hj, wch[J], ac);                                               \
    }

    for (int t = 0; t < T; ++t) {
        const float xt = xrow[t];
        float ai = fmaf(xt, wi_i, bi);
        float af = fmaf(xt, wi_f, bf);
        float ag = fmaf(xt, wi_g, bg);
        float ac = fmaf(xt, wcx, bc);

        STEP_J(0)  STEP_J(1)  STEP_J(2)  STEP_J(3)
        STEP_J(4)  STEP_J(5)  STEP_J(6)  STEP_J(7)
        STEP_J(8)  STEP_J(9)  STEP_J(10) STEP_J(11)
        STEP_J(12) STEP_J(13) STEP_J(14) STEP_J(15)
        STEP_J(16) STEP_J(17) STEP_J(18) STEP_J(19)
        STEP_J(20) STEP_J(21) STEP_J(22) STEP_J(23)
        STEP_J(24) STEP_J(25) STEP_J(26) STEP_J(27)
        STEP_J(28) STEP_J(29) STEP_J(30) STEP_J(31)

        const float ig = sigmoid_f(ai);
        const float fg = sigmoid_f(af);
        const float gg = tanh_f(ag);
        const float cg = sigmoid_f(ac);   // contextual gate (uses previous h)
        c = fmaf(fg, c, ig * gg);
        h = cg * tanh_f(c);               // o-gate is dead in the reference
    }
    #undef STEP_J

    out[(size_t)seq * H + l] = h;
}

extern "C" void kernel_launch(void* const* d_in, const int* in_sizes, int n_in,
                              void* d_out, int out_size, void* d_ws, size_t ws_size,
                              hipStream_t stream) {
    const float* x      = (const float*)d_in[0];
    const float* W_ih   = (const float*)d_in[1];
    const float* W_hh   = (const float*)d_in[2];
    const float* b_ih   = (const float*)d_in[3];
    const float* b_hh   = (const float*)d_in[4];
    const float* W_cg_x = (const float*)d_in[5];
    const float* W_cg_h = (const float*)d_in[6];
    const float* b_cg   = (const float*)d_in[7];
    float* out = (float*)d_out;

    const int grid = NSEQ / SEQ_PER_BLOCK;   // 2304
    cglstm_kernel<<<grid, BLOCK, 0, stream>>>(
        x, W_ih, W_hh, b_ih, b_hh, W_cg_x, W_cg_h, b_cg, out);
}

// Round 3
// 317.362 us; speedup vs baseline: 1.0967x; 1.0967x over previous
//
#include <hip/hip_runtime.h>

// DACGLSTMExpert: 18432 independent CGLSTM sequences, T=120, H=32, DIN=1.
// Lane l of each 32-lane group = hidden index; 2 sequences per wave64.
// h broadcast via LDS: each lane writes h, group reads back with 8 uniform
// ds_read_b128 (HW broadcast). Inner matvec uses packed fp32 (v_pk_fma_f32).
// o-gate is dead code in the reference and skipped (validated round 1).

constexpr int T = 120;
constexpr int H = 32;
constexpr int NSEQ = 2048 * 9;        // 18432
constexpr int SEQ_PER_BLOCK = 8;      // 256 threads / 32 lanes per seq
constexpr int BLOCK = 256;

typedef float v2f __attribute__((ext_vector_type(2)));

#define LOG2E 1.4426950408889634f

__device__ __forceinline__ float fast_rcp(float x) {
    return __builtin_amdgcn_rcpf(x);
}
__device__ __forceinline__ float fast_exp2(float x) {
    return __builtin_amdgcn_exp2f(x);
}
// sigmoid(x) = 1 / (1 + 2^(-x*log2e))
__device__ __forceinline__ float sigmoid_f(float x) {
    return fast_rcp(1.0f + fast_exp2(-LOG2E * x));
}
// tanh(x) = 1 - 2/(2^(2x*log2e) + 1)
__device__ __forceinline__ float tanh_f(float x) {
    return 1.0f - 2.0f * fast_rcp(1.0f + fast_exp2(2.0f * LOG2E * x));
}

__global__ __launch_bounds__(BLOCK, 2) void cglstm_kernel(
    const float* __restrict__ x,      // [NSEQ, T]
    const float* __restrict__ W_ih,   // [4H, 1]
    const float* __restrict__ W_hh,   // [4H, H]
    const float* __restrict__ b_ih,   // [4H]
    const float* __restrict__ b_hh,   // [4H]
    const float* __restrict__ W_cg_x, // [H, 1]
    const float* __restrict__ W_cg_h, // [H, H]
    const float* __restrict__ b_cg,   // [H]
    float* __restrict__ out)          // [NSEQ, H]
{
    __shared__ float xs[SEQ_PER_BLOCK * T];   // 3840 B
    __shared__ float hs[SEQ_PER_BLOCK * H];   // 1024 B

    const int tid = threadIdx.x;
    const int l   = tid & 31;          // hidden index within sequence
    const int sib = tid >> 5;          // sequence-in-block 0..7
    const int seq = blockIdx.x * SEQ_PER_BLOCK + sib;

    // --- stage this block's x rows into LDS (fully coalesced) ---
    const float* xblk = x + (size_t)blockIdx.x * SEQ_PER_BLOCK * T;
    for (int i = tid; i < SEQ_PER_BLOCK * T; i += BLOCK)
        xs[i] = xblk[i];

    // --- per-lane weights in registers, packed as (even j, odd j) pairs ---
    v2f wi2[H / 2], wf2[H / 2], wg2[H / 2], wc2[H / 2];
    {
        const float4* ri = (const float4*)(W_hh + (size_t)(0 * H + l) * H);
        const float4* rf = (const float4*)(W_hh + (size_t)(1 * H + l) * H);
        const float4* rg = (const float4*)(W_hh + (size_t)(2 * H + l) * H);
        const float4* rc = (const float4*)(W_cg_h + (size_t)l * H);
        #pragma unroll
        for (int q = 0; q < H / 4; ++q) {
            float4 vi = ri[q], vf = rf[q], vg = rg[q], vc = rc[q];
            wi2[2*q]   = v2f{vi.x, vi.y};  wi2[2*q+1] = v2f{vi.z, vi.w};
            wf2[2*q]   = v2f{vf.x, vf.y};  wf2[2*q+1] = v2f{vf.z, vf.w};
            wg2[2*q]   = v2f{vg.x, vg.y};  wg2[2*q+1] = v2f{vg.z, vg.w};
            wc2[2*q]   = v2f{vc.x, vc.y};  wc2[2*q+1] = v2f{vc.z, vc.w};
        }
    }
    const float wi_i = W_ih[0 * H + l];
    const float wi_f = W_ih[1 * H + l];
    const float wi_g = W_ih[2 * H + l];
    const float wcx  = W_cg_x[l];
    const float bi   = b_ih[0 * H + l] + b_hh[0 * H + l];
    const float bf   = b_ih[1 * H + l] + b_hh[1 * H + l];
    const float bg   = b_ih[2 * H + l] + b_hh[2 * H + l];
    const float bc   = b_cg[l];

    // initial h = 0 in LDS (each lane owns one slot; no cross-wave sharing)
    hs[sib * H + l] = 0.0f;
    __syncthreads();   // only needed once; cheap

    float c = 0.0f;
    float h_out = 0.0f;
    const float* xrow = xs + sib * T;
    const float4* hp = (const float4*)(hs + sib * H);   // 8 x 16B, 128B aligned
    float* hw = hs + sib * H + l;

    #pragma unroll 1
    for (int t = 0; t < T; ++t) {
        // --- load the group's 32 h values (uniform-address broadcast reads) ---
        float4 h4[8];
        #pragma unroll
        for (int q = 0; q < 8; ++q) h4[q] = hp[q];

        const float xt = xrow[t];
        v2f aI = v2f{fmaf(xt, wi_i, bi), 0.0f};
        v2f aF = v2f{fmaf(xt, wi_f, bf), 0.0f};
        v2f aG = v2f{fmaf(xt, wi_g, bg), 0.0f};
        v2f aC = v2f{fmaf(xt, wcx,  bc), 0.0f};

        #pragma unroll
        for (int q = 0; q < 8; ++q) {
            v2f h01 = v2f{h4[q].x, h4[q].y};
            v2f h23 = v2f{h4[q].z, h4[q].w};
            aI = __builtin_elementwise_fma(h01, wi2[2*q],   aI);
            aF = __builtin_elementwise_fma(h01, wf2[2*q],   aF);
            aG = __builtin_elementwise_fma(h01, wg2[2*q],   aG);
            aC = __builtin_elementwise_fma(h01, wc2[2*q],   aC);
            aI = __builtin_elementwise_fma(h23, wi2[2*q+1], aI);
            aF = __builtin_elementwise_fma(h23, wf2[2*q+1], aF);
            aG = __builtin_elementwise_fma(h23, wg2[2*q+1], aG);
            aC = __builtin_elementwise_fma(h23, wc2[2*q+1], aC);
        }

        const float ig = sigmoid_f(aI.x + aI.y);
        const float fg = sigmoid_f(aF.x + aF.y);
        const float gg = tanh_f(aG.x + aG.y);
        const float cg = sigmoid_f(aC.x + aC.y);   // contextual gate (prev h)
        c = fmaf(fg, c, ig * gg);
        h_out = cg * tanh_f(c);                    // o-gate dead in reference

        // publish h for next step (same-wave consumers only; lgkmcnt handles RAW)
        *hw = h_out;
    }

    out[(size_t)seq * H + l] = h_out;
}

extern "C" void kernel_launch(void* const* d_in, const int* in_sizes, int n_in,
                              void* d_out, int out_size, void* d_ws, size_t ws_size,
                              hipStream_t stream) {
    const float* x      = (const float*)d_in[0];
    const float* W_ih   = (const float*)d_in[1];
    const float* W_hh   = (const float*)d_in[2];
    const float* b_ih   = (const float*)d_in[3];
    const float* b_hh   = (const float*)d_in[4];
    const float* W_cg_x = (const float*)d_in[5];
    const float* W_cg_h = (const float*)d_in[6];
    const float* b_cg   = (const float*)d_in[7];
    float* out = (float*)d_out;

    const int grid = NSEQ / SEQ_PER_BLOCK;   // 2304
    cglstm_kernel<<<grid, BLOCK, 0, stream>>>(
        x, W_ih, W_hh, b_ih, b_hh, W_cg_x, W_cg_h, b_cg, out);
}